// Round 6
// baseline (182.454 us; speedup 1.0000x reference)
//
#include <hip/hip_runtime.h>

typedef _Float16 half_t;
typedef __attribute__((ext_vector_type(8))) _Float16 h8;
typedef __attribute__((ext_vector_type(2))) _Float16 h2v;
typedef __attribute__((ext_vector_type(4))) float f4;
typedef __attribute__((ext_vector_type(2))) float f2v;

// fp32 -> fp16 with inf/NaN killing (fmaxf/fminf return the non-NaN operand).
__device__ __forceinline__ half_t to_h(float v) {
    v = fminf(fmaxf(v, -60000.f), 60000.f);
    return (half_t)v;
}

// ws layout (half elements):
//   w1p : [0, 524288)            [kk=64][nt=16][lane=64][j=8]
//   w2p : [524288, 557056)       [kk=8][nt=8][64][8]
//   swp : [557056, 622592)       [kk=16][nt=8][64][8]
//   xc_g: [622592, 2719744)      [b][t][c=64] fp16 conv output
//   a_g : [2719744, 4816896)     [b][t][c=64] fp16 SE gate
#define W2P_OFF 524288
#define SWP_OFF 557056
#define XCG_OFF 622592
#define AG_OFF  2719744

// ================= kernel A: weight pack + conv + SE gate =================
// blocks 0..255: conv/SE tiles (b = bi>>5, 128 t each). blocks 256..407: pack.
__global__ __launch_bounds__(512) void beat_prep(
    const float* __restrict__ x, const float* __restrict__ conv_w,
    const float* __restrict__ conv_b,
    const float* __restrict__ se_w1, const float* __restrict__ se_b1,
    const float* __restrict__ se_w2, const float* __restrict__ se_b2,
    const float* __restrict__ w1, const float* __restrict__ w2,
    const float* __restrict__ sw,
    half_t* __restrict__ wsH) {

    const int bi = blockIdx.x;
    const int tid = threadIdx.x;

    if (bi >= 256) {    // ---------------- pack blocks ----------------
        int j = (bi - 256) * 512 + tid;       // < 77824 exactly
        if (j < 65536) {                      // w1 [2048][256]
            int L = j & 63, nt = (j >> 6) & 15, kk = j >> 10;
            int k0 = kk * 32 + ((L >> 4) << 3), n = (nt << 4) + (L & 15);
            h8 v;
#pragma unroll
            for (int q = 0; q < 8; q++) v[q] = to_h(w1[(k0 + q) * 256 + n]);
            *(h8*)(wsH + (((kk * 16 + nt) * 64 + L) << 3)) = v;
        } else if (j < 69632) {               // w2 [256][128]
            int o = j - 65536;
            int L = o & 63, nt = (o >> 6) & 7, kk = o >> 9;
            int k0 = kk * 32 + ((L >> 4) << 3), n = (nt << 4) + (L & 15);
            h8 v;
#pragma unroll
            for (int q = 0; q < 8; q++) v[q] = to_h(w2[(k0 + q) * 128 + n]);
            *(h8*)(wsH + W2P_OFF + (((kk * 8 + nt) * 64 + L) << 3)) = v;
        } else {                              // sw [512][128]
            int o = j - 69632;
            int L = o & 63, nt = (o >> 6) & 7, kk = o >> 9;
            int k0 = kk * 32 + ((L >> 4) << 3), n = (nt << 4) + (L & 15);
            h8 v;
#pragma unroll
            for (int q = 0; q < 8; q++) v[q] = to_h(sw[(k0 + q) * 128 + n]);
            *(h8*)(wsH + SWP_OFF + (((kk * 8 + nt) * 64 + L) << 3)) = v;
        }
        return;
    }

    // ---------------- conv/SE tile: b, t in [t0a, t0a+128) ----------------
    __shared__ __align__(16) char smem[54560];
    half_t* xLh  = (half_t*)smem;             // 163*28*2 = 9128 -> 9136
    half_t* xcA  = (half_t*)(smem + 9136);    // 159*72*2 = 22896 -> 32032
    float*  sLf  = (float*)(smem + 32032);    // 64*68*4 = 17408 -> 49440
    float*  hidL = (float*)(smem + 49440);    // 64*20*4 = 5120  -> 54560
    half_t* xc_g = wsH + XCG_OFF;
    half_t* a_g  = wsH + AG_OFF;

    const int b = bi >> 5;
    const int t0a = (bi & 31) << 7;

    // stage x rows t0a-35 .. t0a+127 (163 rows x 13 pairs)
    for (int idx = tid; idx < 163 * 13; idx += 512) {
        int fi = idx / 13, ip = idx - fi * 13;
        int tx = t0a - 35 + fi;
        h2v v;
        if (tx >= 0) {
            const float* xp = x + ((size_t)(b * 4096 + tx)) * 26 + 2 * ip;
            v[0] = to_h(xp[0]); v[1] = to_h(xp[1]);
        } else { v[0] = (_Float16)0.f; v[1] = (_Float16)0.f; }
        *(h2v*)(xLh + fi * 28 + 2 * ip) = v;
    }
    __syncthreads();

    // conv (K=5, 26->64) + relu -> xcA rows [0,159); also write owned rows to xc_g
    {
        int c = tid & 63, f0 = tid >> 6;
        h2v cwr[65];
#pragma unroll
        for (int p = 0; p < 65; p++) {
            int k = p / 13, ip = p - k * 13;
            cwr[p][0] = to_h(conv_w[(k * 26 + 2 * ip) * 64 + c]);
            cwr[p][1] = to_h(conv_w[(k * 26 + 2 * ip + 1) * 64 + c]);
        }
        float bias = conv_b[c];
        for (int f = f0; f < 159; f += 8) {
            int t = t0a + f - 31;
            float r0 = 0.f;
            if (t >= 0) {
                h2v accp; accp[0] = (_Float16)0.f; accp[1] = (_Float16)0.f;
#pragma unroll
                for (int k = 0; k < 5; k++)
#pragma unroll
                    for (int ip = 0; ip < 13; ip++) {
                        h2v xp = *(const h2v*)(xLh + (f + k) * 28 + 2 * ip);
                        accp += xp * cwr[k * 13 + ip];
                    }
                r0 = fmaxf((float)accp[0] + (float)accp[1] + bias, 0.f);
            }
            half_t hv = to_h(r0);
            xcA[f * 72 + c] = hv;
            if (f >= 31) xc_g[((size_t)(b * 4096 + t)) * 64 + c] = hv;  // t >= t0a >= 0
        }
    }
    __syncthreads();

    // means + SE for two 64-t halves
    for (int sub = 0; sub < 2; sub++) {
        const int base = sub * 64;
        {   // sliding means
            int c = tid & 63, mb = tid >> 6;
            float run = 0.f;
#pragma unroll 8
            for (int w = 0; w < 32; w++) run += (float)xcA[(base + mb + w) * 72 + c];
            sLf[mb * 68 + c] = run * (1.f / 32.f);
            for (int m = mb + 8; m < 64; m += 8) {
#pragma unroll
                for (int d = 0; d < 8; d++) {
                    run += (float)xcA[(base + m + 24 + d) * 72 + c];
                    run -= (float)xcA[(base + m - 8 + d) * 72 + c];
                }
                sLf[m * 68 + c] = run * (1.f / 32.f);
            }
        }
        __syncthreads();
        {   // hidden = relu(s @ se_w1 + se_b1)
            int m = tid >> 3, hh = (tid & 7) * 2;
            float acc0 = se_b1[hh], acc1 = se_b1[hh + 1];
            for (int c = 0; c < 64; c++) {
                float sv = sLf[m * 68 + c];
                f2v wq = *(const f2v*)(se_w1 + c * 16 + hh);
                acc0 += sv * wq[0]; acc1 += sv * wq[1];
            }
            hidL[m * 20 + hh] = fmaxf(acc0, 0.f);
            hidL[m * 20 + hh + 1] = fmaxf(acc1, 0.f);
        }
        __syncthreads();
        {   // a = sigmoid(hidden @ se_w2 + se_b2) -> a_g
            int m = tid >> 3, c0 = (tid & 7) * 8;
            float av[8];
#pragma unroll
            for (int q = 0; q < 8; q++) av[q] = se_b2[c0 + q];
            for (int h = 0; h < 16; h++) {
                float hv = hidL[m * 20 + h];
                const f4* wv4 = (const f4*)(se_w2 + h * 64 + c0);
                f4 wq0 = wv4[0], wq1 = wv4[1];
#pragma unroll
                for (int q = 0; q < 4; q++) { av[q] += hv * wq0[q]; av[4 + q] += hv * wq1[q]; }
            }
            h8 ov;
#pragma unroll
            for (int q = 0; q < 8; q++) {
                float zz = fminf(fmaxf(av[q], -30.f), 30.f);
                ov[q] = to_h(1.f / (1.f + __expf(-zz)));
            }
            *(h8*)(a_g + ((size_t)(b * 4096 + t0a + base + m)) * 64 + c0) = ov;
        }
        __syncthreads();
    }
}

// ================= kernel B: pure GEMM pipeline =================
// block = 512 thr (8 waves), one b and 64 consecutive t. Grid = 512.
#define XCS 72   // xcL row stride (halfs), 95 rows, frame f <-> t = t0-31+f
#define Y1S 264  // y1L / hL row stride (halfs), 64 rows

#define MFMA16(a, b, c) __builtin_amdgcn_mfma_f32_16x16x32_f16(a, b, c, 0, 0, 0)

__global__ __launch_bounds__(512, 4) void beat_gemm(
    const float* __restrict__ b1, const float* __restrict__ b2,
    const float* __restrict__ sb,
    const float* __restrict__ wo, const float* __restrict__ bo,
    const half_t* __restrict__ w1p, const half_t* __restrict__ w2p,
    const half_t* __restrict__ swp,
    const half_t* __restrict__ xc_g, const half_t* __restrict__ a_g,
    float* __restrict__ out) {

    __shared__ __align__(16) char smem[49536];
    half_t* xcL = (half_t*)smem;             // 95*72*2 = 13680 -> 13696
    half_t* y1L = (half_t*)(smem + 13696);   // 64*264*2 = 33792 -> 47488
    float*  woL = (float*)(smem + 47488);    // 512 floats -> 49536

    const int tid = threadIdx.x;
    const int bi = blockIdx.x;
    const int b = bi >> 6;
    const int t0 = (bi & 63) << 6;
    const int lane = tid & 63, wv = tid >> 6;     // wv in 0..7
    const int quad = lane >> 4, rl = lane & 15;
    const int mg = wv >> 2;                        // rows mg*32..+32
    const int ng = wv & 3;                         // phase-2 cols ng*64..+64
    const int nq = wv & 3;                         // phase-3/4 cols nq*32..+32

    // ---- stage xcL from xc_g + woL; gate a into registers ----
    if (tid < 256) ((f2v*)woL)[tid] = ((const f2v*)wo)[tid];
    for (int idx = tid; idx < 95 * 8; idx += 512) {
        int fi = idx >> 3, jp = idx & 7;
        int t = t0 - 31 + fi;
        h8 v;
        if (t >= 0) v = *(const h8*)(xc_g + ((size_t)(b * 4096 + t)) * 64 + jp * 8);
        else {
#pragma unroll
            for (int q = 0; q < 8; q++) v[q] = (_Float16)0.f;
        }
        *(h8*)(xcL + fi * XCS + jp * 8) = v;
    }
    h8 avr[2][2];
#pragma unroll
    for (int mt = 0; mt < 2; mt++)
#pragma unroll
        for (int p = 0; p < 2; p++)
            avr[mt][p] = *(const h8*)(a_g + ((size_t)(b * 4096 + t0 + mg * 32 + mt * 16 + rl)) * 64 + p * 32 + quad * 8);
    __syncthreads();

    // ---- phase 2: y1 = relu((a .* window) @ w1 + b1), M=64 K=2048 N=256 ----
    {
        f4 acc[2][4];
#pragma unroll
        for (int mt = 0; mt < 2; mt++)
#pragma unroll
            for (int i = 0; i < 4; i++)
#pragma unroll
                for (int r = 0; r < 4; r++) acc[mt][i][r] = 0.f;
        const h8* w1v = (const h8*)w1p;
        const int fb = ng * 4;
        h8 bA[4], bB[4], bC[4], bD[4];
#pragma unroll
        for (int i = 0; i < 4; i++) bA[i] = w1v[(fb + i) * 64 + lane];
#pragma unroll
        for (int i = 0; i < 4; i++) bB[i] = w1v[(16 + fb + i) * 64 + lane];
#pragma unroll 2
        for (int kk = 0; kk < 64; kk += 2) {
            const int k2 = (kk + 2) & 63, k3 = (kk + 3) & 63;
#pragma unroll
            for (int i = 0; i < 4; i++) bC[i] = w1v[(k2 * 16 + fb + i) * 64 + lane];
#pragma unroll
            for (int i = 0; i < 4; i++) bD[i] = w1v[(k3 * 16 + fb + i) * 64 + lane];
            const int wf = kk >> 1;
            {   // even kk: c0 = quad*8
                const int c0 = quad * 8;
#pragma unroll
                for (int mt = 0; mt < 2; mt++) {
                    int m = mg * 32 + mt * 16 + rl;
                    h8 xv = *(const h8*)(xcL + (m + wf) * XCS + c0);
                    h8 af = xv * avr[mt][0];
#pragma unroll
                    for (int i = 0; i < 4; i++) acc[mt][i] = MFMA16(af, bA[i], acc[mt][i]);
                }
            }
            {   // odd kk: c0 = 32 + quad*8
                const int c0 = 32 + quad * 8;
#pragma unroll
                for (int mt = 0; mt < 2; mt++) {
                    int m = mg * 32 + mt * 16 + rl;
                    h8 xv = *(const h8*)(xcL + (m + wf) * XCS + c0);
                    h8 af = xv * avr[mt][1];
#pragma unroll
                    for (int i = 0; i < 4; i++) acc[mt][i] = MFMA16(af, bB[i], acc[mt][i]);
                }
            }
#pragma unroll
            for (int i = 0; i < 4; i++) { bA[i] = bC[i]; bB[i] = bD[i]; }
        }
#pragma unroll
        for (int i = 0; i < 4; i++) {
            int n = ng * 64 + i * 16 + rl;
            float bb = b1[n];
#pragma unroll
            for (int mt = 0; mt < 2; mt++)
#pragma unroll
                for (int r = 0; r < 4; r++) {
                    int m = mg * 32 + mt * 16 + quad * 4 + r;
                    y1L[m * Y1S + n] = to_h(fmaxf(acc[mt][i][r] + bb, 0.f));
                }
        }
    }
    __syncthreads();

    // ---- phase 3: h2 = relu(y1 @ w2 + b2), M=64 K=256 N=128, kept in regs ----
    f4 acc2[2][2];
#pragma unroll
    for (int mt = 0; mt < 2; mt++)
#pragma unroll
        for (int j = 0; j < 2; j++)
#pragma unroll
            for (int r = 0; r < 4; r++) acc2[mt][j][r] = 0.f;
    {
        const h8* w2v = (const h8*)w2p;
        const int fb2 = nq * 2;
        h8 c0f = w2v[(fb2 + 0) * 64 + lane];
        h8 c1f = w2v[(fb2 + 1) * 64 + lane];
#pragma unroll 2
        for (int kk = 0; kk < 8; kk++) {
            int kn = (kk + 1) & 7;
            h8 n0 = w2v[(kn * 8 + fb2 + 0) * 64 + lane];
            h8 n1 = w2v[(kn * 8 + fb2 + 1) * 64 + lane];
#pragma unroll
            for (int mt = 0; mt < 2; mt++) {
                h8 av = *(const h8*)(y1L + (mg * 32 + mt * 16 + rl) * Y1S + kk * 32 + quad * 8);
                acc2[mt][0] = MFMA16(av, c0f, acc2[mt][0]);
                acc2[mt][1] = MFMA16(av, c1f, acc2[mt][1]);
            }
            c0f = n0; c1f = n1;
        }
    }

    // ---- phase 4: h_short = relu((a .* window[-8:]) @ sw + sb), K=512 N=128 ----
    f4 accS[2][2];
#pragma unroll
    for (int mt = 0; mt < 2; mt++)
#pragma unroll
        for (int j = 0; j < 2; j++)
#pragma unroll
            for (int r = 0; r < 4; r++) accS[mt][j][r] = 0.f;
    {
        const h8* swv = (const h8*)swp;
        const int fb2 = nq * 2;
        h8 c0f = swv[(fb2 + 0) * 64 + lane];
        h8 c1f = swv[(fb2 + 1) * 64 + lane];
#pragma unroll 2
        for (int kk = 0; kk < 16; kk++) {
            int kn = (kk + 1) & 15;
            h8 n0 = swv[(kn * 8 + fb2 + 0) * 64 + lane];
            h8 n1 = swv[(kn * 8 + fb2 + 1) * 64 + lane];
            const int wf = 24 + (kk >> 1);
            const int c0 = ((kk & 1) << 5) + quad * 8;
#pragma unroll
            for (int mt = 0; mt < 2; mt++) {
                int m = mg * 32 + mt * 16 + rl;
                h8 xv = *(const h8*)(xcL + (m + wf) * XCS + c0);
                h8 af = xv * avr[mt][kk & 1];
                accS[mt][0] = MFMA16(af, c0f, accS[mt][0]);
                accS[mt][1] = MFMA16(af, c1f, accS[mt][1]);
            }
            c0f = n0; c1f = n1;
        }
    }
    __syncthreads();  // phase-3 reads of y1L done before overwrite

    // ---- phase 5a: hL[m][0:128]=relu(h2), hL[m][128:256]=relu(h_short) ----
    {
#pragma unroll
        for (int j = 0; j < 2; j++) {
            int n = nq * 32 + j * 16 + rl;
            float bb2 = b2[n], bbs = sb[n];
#pragma unroll
            for (int mt = 0; mt < 2; mt++)
#pragma unroll
                for (int r = 0; r < 4; r++) {
                    int m = mg * 32 + mt * 16 + quad * 4 + r;
                    y1L[m * Y1S + n]       = to_h(fmaxf(acc2[mt][j][r] + bb2, 0.f));
                    y1L[m * Y1S + 128 + n] = to_h(fmaxf(accS[mt][j][r] + bbs, 0.f));
                }
        }
    }
    __syncthreads();

    // ---- phase 5b: out = sigmoid(h @ wo + bo), 128 threads ----
    if (tid < 128) {
        int m = tid >> 1, o = tid & 1;
        float z = bo[o];
        const half_t* hrow = y1L + m * Y1S;
        for (int nb = 0; nb < 32; nb++) {
            h8 hv = *(const h8*)(hrow + nb * 8);
#pragma unroll
            for (int q = 0; q < 8; q++)
                z += (float)hv[q] * woL[(nb * 8 + q) * 2 + o];
        }
        z = fminf(fmaxf(z, -30.f), 30.f);
        float sg = 1.f / (1.f + __expf(-z));
        out[((size_t)(b * 4096 + t0 + m)) * 2 + o] = sg;
    }
}

extern "C" void kernel_launch(void* const* d_in, const int* in_sizes, int n_in,
                              void* d_out, int out_size, void* d_ws, size_t ws_size,
                              hipStream_t stream) {
    const float* x      = (const float*)d_in[0];
    const float* conv_w = (const float*)d_in[1];
    const float* conv_b = (const float*)d_in[2];
    const float* se_w1  = (const float*)d_in[3];
    const float* se_b1  = (const float*)d_in[4];
    const float* se_w2  = (const float*)d_in[5];
    const float* se_b2  = (const float*)d_in[6];
    const float* w1     = (const float*)d_in[7];
    const float* b1     = (const float*)d_in[8];
    const float* w2     = (const float*)d_in[9];
    const float* b2     = (const float*)d_in[10];
    const float* sw     = (const float*)d_in[11];
    const float* sb     = (const float*)d_in[12];
    const float* wo     = (const float*)d_in[13];
    const float* bo     = (const float*)d_in[14];
    half_t* wsH = (half_t*)d_ws;

    hipLaunchKernelGGL(beat_prep, dim3(408), dim3(512), 0, stream,
                       x, conv_w, conv_b, se_w1, se_b1, se_w2, se_b2, w1, w2, sw, wsH);
    hipLaunchKernelGGL(beat_gemm, dim3(512), dim3(512), 0, stream,
                       b1, b2, sb, wo, bo,
                       wsH, wsH + W2P_OFF, wsH + SWP_OFF,
                       wsH + XCG_OFF, wsH + AG_OFF,
                       (float*)d_out);
}

// Round 7
// 147.483 us; speedup vs baseline: 1.2371x; 1.2371x over previous
//
#include <hip/hip_runtime.h>

typedef _Float16 half_t;
typedef __attribute__((ext_vector_type(8))) _Float16 h8;
typedef __attribute__((ext_vector_type(2))) _Float16 h2v;
typedef __attribute__((ext_vector_type(4))) float f4;
typedef __attribute__((ext_vector_type(2))) float f2v;

// fp32 -> fp16 with inf/NaN killing (fmaxf/fminf return the non-NaN operand).
__device__ __forceinline__ half_t to_h(float v) {
    v = fminf(fmaxf(v, -60000.f), 60000.f);
    return (half_t)v;
}

// ---------------- pack kernel: bilaterally-coalesced fp32 -> fp16 MFMA-B frags ----------
// ws layout (half elements):
//   w1p: [0, 524288)          [kk=64][nt=16][lane=64][j=8]
//   w2p: [524288, 557056)     [kk=8][nt=8][64][8]
//   swp: [557056, 622592)     [kk=16][nt=8][64][8]
//   cwp: [622592, 630912)     [p=k*13+ip][c=64][r=2]
__global__ void pack_k(const float* __restrict__ w1, const float* __restrict__ w2,
                       const float* __restrict__ sw, const float* __restrict__ cw,
                       half_t* __restrict__ wsH) {
    int i = blockIdx.x * 256 + threadIdx.x;
    if (i < 65536) {                        // w1 [2048][256]: 65536 h8 jobs
        int L = i & 63, nt = (i >> 6) & 15, kk = i >> 10;
        int k0 = kk * 32 + ((L >> 4) << 3), n = (nt << 4) + (L & 15);
        h8 v;
#pragma unroll
        for (int j = 0; j < 8; j++) v[j] = to_h(w1[(k0 + j) * 256 + n]);
        *(h8*)(wsH + ((((kk * 16 + nt) * 64 + L)) << 3)) = v;
    } else if (i < 69632) {                 // w2 [256][128]: 4096 jobs
        int o = i - 65536;
        int L = o & 63, nt = (o >> 6) & 7, kk = o >> 9;
        int k0 = kk * 32 + ((L >> 4) << 3), n = (nt << 4) + (L & 15);
        h8 v;
#pragma unroll
        for (int j = 0; j < 8; j++) v[j] = to_h(w2[(k0 + j) * 128 + n]);
        *(h8*)(wsH + 524288 + ((((kk * 8 + nt) * 64 + L)) << 3)) = v;
    } else if (i < 77824) {                 // sw [512][128]: 8192 jobs
        int o = i - 69632;
        int L = o & 63, nt = (o >> 6) & 7, kk = o >> 9;
        int k0 = kk * 32 + ((L >> 4) << 3), n = (nt << 4) + (L & 15);
        h8 v;
#pragma unroll
        for (int j = 0; j < 8; j++) v[j] = to_h(sw[(k0 + j) * 128 + n]);
        *(h8*)(wsH + 557056 + ((((kk * 8 + nt) * 64 + L)) << 3)) = v;
    } else if (i < 86144) {                 // cw [5][26][64]: 8320 element jobs
        int o = i - 77824;
        int c = o & 63, rest = o >> 6;
        int k = rest / 26, ci = rest - k * 26;
        int ip = ci >> 1, r = ci & 1;
        wsH[622592 + ((k * 13 + ip) * 64 + c) * 2 + r] = to_h(cw[o]);
    }
}

// ---------------- main fused kernel ----------------
// block = 512 thr (8 waves), one b and 64 consecutive t. Grid = 8*64 = 512 (2 blocks/CU).
// GEMM mapping: each wave owns ALL 64 rows (mt=4) and 1/8 of N -> 2x B-reuse vs 4-way split.
#define XCS 72   // xcL row stride (halfs), 95 rows, frame f <-> t = t0-31+f
#define ALS 72   // aL row stride (halfs), 64 rows
#define Y1S 264  // y1L / hL row stride (halfs), 64 rows
#define SLS 68   // sLf row stride (floats)
#define HLS 20   // hidL row stride (floats)

#define MFMA16(a, b, c) __builtin_amdgcn_mfma_f32_16x16x32_f16(a, b, c, 0, 0, 0)

__global__ __launch_bounds__(512, 4) void beat_main(
    const float* __restrict__ x,
    const float* __restrict__ conv_b,
    const float* __restrict__ se_w1, const float* __restrict__ se_b1,
    const float* __restrict__ se_w2, const float* __restrict__ se_b2,
    const float* __restrict__ b1, const float* __restrict__ b2,
    const float* __restrict__ sb,
    const float* __restrict__ wo, const float* __restrict__ bo,
    const half_t* __restrict__ w1p, const half_t* __restrict__ w2p,
    const half_t* __restrict__ swp, const half_t* __restrict__ cwp,
    float* __restrict__ out) {

    __shared__ __align__(16) char smem[58752];
    half_t* xcL = (half_t*)smem;             // 95*72*2 = 13680 -> pad 13696
    half_t* aL  = (half_t*)(smem + 13696);   // 64*72*2 = 9216 -> 22912
    char*   U   = smem + 22912;              // 33792-byte phase union
    half_t* xLh = (half_t*)U;                // phase0: 99*28 halfs = 5544
    float*  sLf = (float*)U;                 // phase1: 64*68 floats = 17408
    float*  hidL= (float*)(U + 17408);       // phase1: 64*20 floats = 5120
    half_t* y1L = (half_t*)U;                // phase2+: 64*264 halfs = 33792
    float*  woL = (float*)(smem + 56704);    // 512 floats -> 58752

    const int tid = threadIdx.x;
    const int bi = blockIdx.x;
    const int b = bi >> 6;
    const int t0 = (bi & 63) << 6;
    const int lane = tid & 63, wv = tid >> 6;     // wv in 0..7
    const int quad = lane >> 4, rl = lane & 15;

    // ---- phase 0a: stage x (fp16 pairs) + wo ----
    if (tid < 256) ((f2v*)woL)[tid] = ((const f2v*)wo)[tid];   // 512 floats
    for (int idx = tid; idx < 99 * 13; idx += 512) {
        int fi = idx / 13, ip = idx - fi * 13;
        int tx = t0 - 35 + fi;
        h2v v;
        if (tx >= 0) {
            const float* xp = x + ((size_t)(b * 4096 + tx)) * 26 + 2 * ip;
            v[0] = to_h(xp[0]); v[1] = to_h(xp[1]);
        } else { v[0] = (_Float16)0.f; v[1] = (_Float16)0.f; }
        *(h2v*)(xLh + fi * 28 + 2 * ip) = v;
    }
    __syncthreads();

    // ---- phase 0b: causal conv (K=5, 26->64) + relu -> xcL (fp16), 95 rows ----
    {
        int c = tid & 63, f0 = tid >> 6;          // f0 in 0..7
        h2v cwr[65];
        const h2v* cwg = (const h2v*)cwp;         // coalesced b32 per lane
#pragma unroll
        for (int p = 0; p < 65; p++) cwr[p] = cwg[p * 64 + c];
        float bias = conv_b[c];
        for (int f = f0; f < 95; f += 8) {
            int t = t0 - 31 + f;
            float r0 = 0.f;
            if (t >= 0) {
                h2v accp; accp[0] = (_Float16)0.f; accp[1] = (_Float16)0.f;
#pragma unroll
                for (int k = 0; k < 5; k++)
#pragma unroll
                    for (int ip = 0; ip < 13; ip++) {
                        h2v xp = *(const h2v*)(xLh + (f + k) * 28 + 2 * ip);
                        accp += xp * cwr[k * 13 + ip];
                    }
                r0 = fmaxf((float)accp[0] + (float)accp[1] + bias, 0.f);
            }
            xcL[f * XCS + c] = to_h(r0);
        }
    }
    __syncthreads();

    // ---- phase 1a: sliding window means s[m][c], m in [0,64) ----
    {
        int c = tid & 63, mb = tid >> 6;          // mb in 0..7
        float run = 0.f;
#pragma unroll 8
        for (int w = 0; w < 32; w++) run += (float)xcL[(mb + w) * XCS + c];
        sLf[mb * SLS + c] = run * (1.f / 32.f);
        for (int m = mb + 8; m < 64; m += 8) {
#pragma unroll
            for (int d = 0; d < 8; d++) {
                run += (float)xcL[(m + 24 + d) * XCS + c];
                run -= (float)xcL[(m - 8 + d) * XCS + c];
            }
            sLf[m * SLS + c] = run * (1.f / 32.f);
        }
    }
    __syncthreads();

    // ---- phase 1b: SE hidden = relu(s @ se_w1 + se_b1), 64 m x 16 h ----
    {
        int m = tid >> 3, hh = (tid & 7) * 2;
        float acc0 = se_b1[hh], acc1 = se_b1[hh + 1];
        for (int c = 0; c < 64; c++) {
            float sv = sLf[m * SLS + c];
            f2v wq = *(const f2v*)(se_w1 + c * 16 + hh);
            acc0 += sv * wq[0]; acc1 += sv * wq[1];
        }
        hidL[m * HLS + hh] = fmaxf(acc0, 0.f);
        hidL[m * HLS + hh + 1] = fmaxf(acc1, 0.f);
    }
    __syncthreads();

    // ---- phase 1c: a = sigmoid(hidden @ se_w2 + se_b2) -> aL (fp16) ----
    {
        int m = tid >> 3, c0 = (tid & 7) * 8;
        float av[8];
#pragma unroll
        for (int j = 0; j < 8; j++) av[j] = se_b2[c0 + j];
        for (int h = 0; h < 16; h++) {
            float hv = hidL[m * HLS + h];
            const f4* wv4 = (const f4*)(se_w2 + h * 64 + c0);
            f4 wq0 = wv4[0], wq1 = wv4[1];
#pragma unroll
            for (int j = 0; j < 4; j++) { av[j] += hv * wq0[j]; av[4 + j] += hv * wq1[j]; }
        }
#pragma unroll
        for (int j = 0; j < 8; j++) {
            float zz = fminf(fmaxf(av[j], -30.f), 30.f);
            float s = 1.f / (1.f + __expf(-zz));
            aL[m * ALS + c0 + j] = to_h(s);
        }
    }
    __syncthreads();

    // ---- gates into registers: avr[mt][half], rows mt*16+rl, channels half*32+quad*8 ----
    h8 avr[4][2];
#pragma unroll
    for (int mt = 0; mt < 4; mt++)
#pragma unroll
        for (int p = 0; p < 2; p++)
            avr[mt][p] = *(const h8*)(aL + (mt * 16 + rl) * ALS + p * 32 + quad * 8);

    // ---- phase 2: y1 = relu((a .* window) @ w1 + b1), M=64 K=2048 N=256 ----
    // wave wv: all 64 rows, cols wv*32..+32 (nt = wv*2+i). Prefetch distance 2 kk-steps.
    {
        f4 acc[4][2];
#pragma unroll
        for (int mt = 0; mt < 4; mt++)
#pragma unroll
            for (int i = 0; i < 2; i++)
#pragma unroll
                for (int r = 0; r < 4; r++) acc[mt][i][r] = 0.f;
        const h8* w1v = (const h8*)w1p;
        const int fb = wv * 2;
        h8 bA[2], bB[2], bC[2], bD[2];
#pragma unroll
        for (int i = 0; i < 2; i++) bA[i] = w1v[(fb + i) * 64 + lane];
#pragma unroll
        for (int i = 0; i < 2; i++) bB[i] = w1v[(16 + fb + i) * 64 + lane];
#pragma unroll 2
        for (int kk = 0; kk < 64; kk += 2) {
            const int k2 = (kk + 2) & 63, k3 = (kk + 3) & 63;  // wrap harmless on last iter
#pragma unroll
            for (int i = 0; i < 2; i++) bC[i] = w1v[(k2 * 16 + fb + i) * 64 + lane];
#pragma unroll
            for (int i = 0; i < 2; i++) bD[i] = w1v[(k3 * 16 + fb + i) * 64 + lane];
            const int wf = kk >> 1;
            {   // even kk: channels 0..31 -> avr[.][0]
                const int c0 = quad * 8;
#pragma unroll
                for (int mt = 0; mt < 4; mt++) {
                    int m = mt * 16 + rl;
                    h8 xv = *(const h8*)(xcL + (m + wf) * XCS + c0);
                    h8 af = xv * avr[mt][0];
                    acc[mt][0] = MFMA16(af, bA[0], acc[mt][0]);
                    acc[mt][1] = MFMA16(af, bA[1], acc[mt][1]);
                }
            }
            {   // odd kk: channels 32..63 -> avr[.][1]
                const int c0 = 32 + quad * 8;
#pragma unroll
                for (int mt = 0; mt < 4; mt++) {
                    int m = mt * 16 + rl;
                    h8 xv = *(const h8*)(xcL + (m + wf) * XCS + c0);
                    h8 af = xv * avr[mt][1];
                    acc[mt][0] = MFMA16(af, bB[0], acc[mt][0]);
                    acc[mt][1] = MFMA16(af, bB[1], acc[mt][1]);
                }
            }
#pragma unroll
            for (int i = 0; i < 2; i++) { bA[i] = bC[i]; bB[i] = bD[i]; }
        }
#pragma unroll
        for (int i = 0; i < 2; i++) {
            int n = wv * 32 + i * 16 + rl;
            float bb = b1[n];
#pragma unroll
            for (int mt = 0; mt < 4; mt++)
#pragma unroll
                for (int r = 0; r < 4; r++) {
                    int m = mt * 16 + quad * 4 + r;
                    y1L[m * Y1S + n] = to_h(fmaxf(acc[mt][i][r] + bb, 0.f));
                }
        }
    }
    __syncthreads();

    // ---- phase 3: h2 = relu(y1 @ w2 + b2), M=64 K=256 N=128; wave wv: cols wv*16..+16 ----
    f4 acc2[4];
#pragma unroll
    for (int mt = 0; mt < 4; mt++)
#pragma unroll
        for (int r = 0; r < 4; r++) acc2[mt][r] = 0.f;
    {
        const h8* w2v = (const h8*)w2p;
        h8 cf = w2v[wv * 64 + lane];
#pragma unroll 2
        for (int kk = 0; kk < 8; kk++) {
            int kn = (kk + 1) & 7;
            h8 nf = w2v[(kn * 8 + wv) * 64 + lane];
#pragma unroll
            for (int mt = 0; mt < 4; mt++) {
                h8 av = *(const h8*)(y1L + (mt * 16 + rl) * Y1S + kk * 32 + quad * 8);
                acc2[mt] = MFMA16(av, cf, acc2[mt]);
            }
            cf = nf;
        }
    }

    // ---- phase 4: h_short = relu((a .* window[-8:]) @ sw + sb), K=512 N=128 ----
    f4 accS[4];
#pragma unroll
    for (int mt = 0; mt < 4; mt++)
#pragma unroll
        for (int r = 0; r < 4; r++) accS[mt][r] = 0.f;
    {
        const h8* swv = (const h8*)swp;
        h8 cf = swv[wv * 64 + lane];
#pragma unroll 2
        for (int kk = 0; kk < 16; kk++) {
            int kn = (kk + 1) & 15;
            h8 nf = swv[(kn * 8 + wv) * 64 + lane];
            const int wf = 24 + (kk >> 1);
            const int c0 = ((kk & 1) << 5) + quad * 8;
#pragma unroll
            for (int mt = 0; mt < 4; mt++) {
                int m = mt * 16 + rl;
                h8 xv = *(const h8*)(xcL + (m + wf) * XCS + c0);
                h8 af = xv * avr[mt][kk & 1];
                accS[mt] = MFMA16(af, cf, accS[mt]);
            }
            cf = nf;
        }
    }
    __syncthreads();  // phase-3 reads of y1L done before overwrite

    // ---- phase 5a: hL[m][0:128]=relu(h2), hL[m][128:256]=relu(h_short) ----
    {
        int n = wv * 16 + rl;
        float bb2 = b2[n], bbs = sb[n];
#pragma unroll
        for (int mt = 0; mt < 4; mt++)
#pragma unroll
            for (int r = 0; r < 4; r++) {
                int m = mt * 16 + quad * 4 + r;
                y1L[m * Y1S + n]       = to_h(fmaxf(acc2[mt][r] + bb2, 0.f));
                y1L[m * Y1S + 128 + n] = to_h(fmaxf(accS[mt][r] + bbs, 0.f));
            }
    }
    __syncthreads();

    // ---- phase 5b: out = sigmoid(h @ wo + bo), 128 threads ----
    if (tid < 128) {
        int m = tid >> 1, o = tid & 1;
        float z = bo[o];
        const half_t* hrow = y1L + m * Y1S;
        for (int nb = 0; nb < 32; nb++) {
            h8 hv = *(const h8*)(hrow + nb * 8);
#pragma unroll
            for (int q = 0; q < 8; q++)
                z += (float)hv[q] * woL[(nb * 8 + q) * 2 + o];
        }
        z = fminf(fmaxf(z, -30.f), 30.f);
        float sg = 1.f / (1.f + __expf(-z));
        out[((size_t)(b * 4096 + t0 + m)) * 2 + o] = sg;
    }
}

extern "C" void kernel_launch(void* const* d_in, const int* in_sizes, int n_in,
                              void* d_out, int out_size, void* d_ws, size_t ws_size,
                              hipStream_t stream) {
    const float* x      = (const float*)d_in[0];
    const float* conv_w = (const float*)d_in[1];
    const float* conv_b = (const float*)d_in[2];
    const float* se_w1  = (const float*)d_in[3];
    const float* se_b1  = (const float*)d_in[4];
    const float* se_w2  = (const float*)d_in[5];
    const float* se_b2  = (const float*)d_in[6];
    const float* w1     = (const float*)d_in[7];
    const float* b1     = (const float*)d_in[8];
    const float* w2     = (const float*)d_in[9];
    const float* b2     = (const float*)d_in[10];
    const float* sw     = (const float*)d_in[11];
    const float* sb     = (const float*)d_in[12];
    const float* wo     = (const float*)d_in[13];
    const float* bo     = (const float*)d_in[14];
    half_t* wsH = (half_t*)d_ws;

    hipLaunchKernelGGL(pack_k, dim3(337), dim3(256), 0, stream, w1, w2, sw, conv_w, wsH);
    hipLaunchKernelGGL(beat_main, dim3(512), dim3(512), 0, stream,
                       x, conv_b, se_w1, se_b1, se_w2, se_b2, b1, b2, sb, wo, bo,
                       wsH, wsH + 524288, wsH + 557056, wsH + 622592,
                       (float*)d_out);
}